// Round 1
// baseline (675.435 us; speedup 1.0000x reference)
//
#include <hip/hip_runtime.h>

// Problem: segment-mean of x[:,0] over sorted `batch` -> out[4096]
//   x:          (1e6, 128) f32   (d_in[0])  -- only column 0 used
//   edge_index: (2, 1e6)   int   (d_in[1])  -- UNUSED
//   edge_attr:  (1e6, 16)  f32   (d_in[2])  -- UNUSED
//   batch:      (1e6,)     int   (d_in[3])  -- SORTED, values in [0, 4096)
//
// v2 design: the previous kernel gathered x[:,0] at a 512B stride (every 4th
// 128B line, 4B used/line) -- DRAM row-activate-limited at ~0.5 TB/s
// effective (~255 us). This version STREAMS x contiguously at full BW
// (512 MB @ ~6.3 TB/s ~= 82 us): each 256-thread block reads a 128 KB slab
// (256 rows) with coalesced float4 loads, compacts the 256 column-0 values
// via LDS, then runs a 64-lane segmented shfl-up scan (valid because batch
// is sorted) with one atomic pair per cross-thread run tail (~20k total).

#define N_GRAPHS       4096
#define D_FEAT         128
#define BLOCK          256
#define ROWS_PER_BLOCK 256   // BLOCK threads * 32 float4/thread / 32 float4/row
#define F4_PER_ROW     (D_FEAT / 4)   // 32

__global__ __launch_bounds__(256) void zero_ws_kernel(float* ws, int n) {
    int i = blockIdx.x * blockDim.x + threadIdx.x;
    if (i < n) ws[i] = 0.0f;
}

__global__ __launch_bounds__(BLOCK) void accum_kernel(
        const float4* __restrict__ x4,
        const int*    __restrict__ batch,
        float* __restrict__ sums,
        float* __restrict__ counts,
        int n) {
    __shared__ float col0[ROWS_PER_BLOCK];

    const int tid = threadIdx.x;
    const long long row_base = (long long)blockIdx.x * ROWS_PER_BLOCK;
    const long long f4_base  = row_base * F4_PER_ROW;

    // ---- phase 1: stream the block's 128 KB slab, keep column 0 ----------
    // Useful element: float4 index i with i % 32 == 0 (component .x). With
    // i = f4_base + j*BLOCK + tid and f4_base, j*BLOCK both = 0 (mod 32),
    // that's exactly the lanes tid % 32 == 0; row-in-tile = tid/32 + j*8.
    if (row_base + ROWS_PER_BLOCK <= (long long)n) {
        #pragma unroll 8
        for (int j = 0; j < 32; ++j) {
            float4 v = x4[f4_base + (long long)j * BLOCK + tid];
            // Keep the full 16B load, in ALL lanes: without this the
            // compiler narrows dwordx4->dword and sinks it under the
            // (tid&31)==0 predicate -- recreating the 512B-stride gather.
            asm volatile("" :: "v"(v.x), "v"(v.y), "v"(v.z), "v"(v.w));
            if ((tid & 31) == 0) col0[(tid >> 5) + j * 8] = v.x;
        }
    } else {
        // partial tail block (n % 256 != 0)
        const long long f4_n = (long long)n * F4_PER_ROW;
        for (int j = 0; j < 32; ++j) {
            long long i = f4_base + (long long)j * BLOCK + tid;
            if (i < f4_n) {
                float4 v = x4[i];
                asm volatile("" :: "v"(v.x), "v"(v.y), "v"(v.z), "v"(v.w));
                if ((tid & 31) == 0) col0[(tid >> 5) + j * 8] = v.x;
            }
        }
    }
    __syncthreads();

    // ---- phase 2: 1 node/thread, wave-segmented inclusive scan -----------
    const int lane = tid & 63;
    long long row  = row_base + tid;

    int   seg = -1;
    float sum = 0.0f, cnt = 0.0f;
    if (row < (long long)n) {
        seg = batch[row];
        sum = col0[tid];
        cnt = 1.0f;
    }

    // Segmented inclusive scan across the 64-lane wave. Valid because batch
    // is sorted: equal segs at distance `off` implies the whole span equal.
    #pragma unroll
    for (int off = 1; off < 64; off <<= 1) {
        float s2 = __shfl_up(sum, off);
        float c2 = __shfl_up(cnt, off);
        int   g2 = __shfl_up(seg, off);
        if (lane >= off && g2 == seg) { sum += s2; cnt += c2; }
    }

    // One atomic pair per cross-thread run tail.
    int  seg_next = __shfl_down(seg, 1);
    bool tail     = (lane == 63) || (seg_next != seg);
    if (seg >= 0 && tail) {
        atomicAdd(sums + seg, sum);
        atomicAdd(counts + seg, cnt);
    }
}

__global__ __launch_bounds__(256) void finalize_kernel(
        const float* __restrict__ sums,
        const float* __restrict__ counts,
        float* __restrict__ out, int n) {
    int g = blockIdx.x * blockDim.x + threadIdx.x;
    if (g < n) out[g] = sums[g] / counts[g];
}

extern "C" void kernel_launch(void* const* d_in, const int* in_sizes, int n_in,
                              void* d_out, int out_size, void* d_ws, size_t ws_size,
                              hipStream_t stream) {
    const float4* x4    = (const float4*)d_in[0];
    const int*    batch = (const int*)  d_in[3];
    int n_nodes = in_sizes[3];                 // 1,000,000

    float* sums   = (float*)d_ws;              // [N_GRAPHS]
    float* counts = sums + N_GRAPHS;           // [N_GRAPHS]

    // 1) zero accumulators (ws is poisoned 0xAA before every timed launch)
    {
        int n = 2 * N_GRAPHS;
        zero_ws_kernel<<<(n + 255) / 256, 256, 0, stream>>>((float*)d_ws, n);
    }

    // 2) accumulate per-segment (sum, count), streaming x at full BW
    int n_blocks = (n_nodes + ROWS_PER_BLOCK - 1) / ROWS_PER_BLOCK;  // 3907
    accum_kernel<<<n_blocks, BLOCK, 0, stream>>>(
        x4, batch, sums, counts, n_nodes);

    // 3) divide
    finalize_kernel<<<(out_size + 255) / 256, 256, 0, stream>>>(
        sums, counts, (float*)d_out, out_size);
}

// Round 2
// 599.906 us; speedup vs baseline: 1.1259x; 1.1259x over previous
//
#include <hip/hip_runtime.h>

// Problem: segment-mean of x[:,0] over sorted `batch` -> out[4096]
//   x:          (1e6, 128) f32   (d_in[0])  -- only column 0 used (512B-stride gather)
//   edge_index: (2, 1e6)   int   (d_in[1])  -- UNUSED
//   edge_attr:  (1e6, 16)  f32   (d_in[2])  -- UNUSED
//   batch:      (1e6,)     int   (d_in[3])  -- SORTED, values in [0, 4096)
//
// v3 = v1 with ONE change: plain cached loads instead of
// __builtin_nontemporal_load. Theory: nt policy on gfx950 skips L2
// allocation, so each 4B gather became its own narrow DRAM transaction
// (~0.5 TB/s effective, ~250us). Cached loads let the 64 lanes of a wave
// share 128B line fills through L2; mandatory traffic is every 4th line of
// x (1M lines = 132 MB incl. batch) ~= 25-60us at HBM.
// (v2's full-512MB stream proved 4x the mandatory traffic and was net
// slower; reverted.)

#define N_GRAPHS 4096
#define D_FEAT   128

__global__ __launch_bounds__(256) void zero_ws_kernel(float* ws, int n) {
    int i = blockIdx.x * blockDim.x + threadIdx.x;
    if (i < n) ws[i] = 0.0f;
}

__global__ __launch_bounds__(256) void accum_kernel(
        const float* __restrict__ x,
        const int*   __restrict__ batch,
        float* __restrict__ sums,
        float* __restrict__ counts,
        int n_chunks, int n) {
    int t    = blockIdx.x * blockDim.x + threadIdx.x;
    int lane = threadIdx.x & 63;

    int   seg = -1;
    float sum = 0.0f, cnt = 0.0f;

    if (t < n_chunks) {
        size_t base = (size_t)t * 4;
        if (base + 3 < (size_t)n) {
            int4 b = ((const int4*)batch)[t];
            // plain cached loads (the single change vs the 590us version)
            float v0 = x[(base + 0) * D_FEAT];
            float v1 = x[(base + 1) * D_FEAT];
            float v2 = x[(base + 2) * D_FEAT];
            float v3 = x[(base + 3) * D_FEAT];
            if (b.x == b.w) {
                // uniform chunk (common): one piece for the wave scan
                seg = b.x; sum = v0 + v1 + v2 + v3; cnt = 4.0f;
            } else {
                // boundary chunk (rare): flush runs directly, stay sentinel
                int   bs[4] = {b.x, b.y, b.z, b.w};
                float vs[4] = {v0, v1, v2, v3};
                int cs = bs[0]; float s = vs[0], c = 1.0f;
                #pragma unroll
                for (int j = 1; j < 4; ++j) {
                    if (bs[j] == cs) { s += vs[j]; c += 1.0f; }
                    else {
                        atomicAdd(sums + cs, s); atomicAdd(counts + cs, c);
                        cs = bs[j]; s = vs[j]; c = 1.0f;
                    }
                }
                atomicAdd(sums + cs, s); atomicAdd(counts + cs, c);
            }
        } else {
            // partial tail chunk (n % 4 != 0): scalar, direct atomics
            for (size_t j = base; j < (size_t)n; ++j) {
                int g = batch[j];
                atomicAdd(sums + g, x[j * D_FEAT]);
                atomicAdd(counts + g, 1.0f);
            }
        }
    }

    // Segmented inclusive scan across the 64-lane wave (valid: batch sorted,
    // so equal segs at distance `off` implies the whole span is equal; a
    // boundary-chunk sentinel lane can never separate two same-seg lanes).
    #pragma unroll
    for (int off = 1; off < 64; off <<= 1) {
        float s2 = __shfl_up(sum, off);
        float c2 = __shfl_up(cnt, off);
        int   g2 = __shfl_up(seg, off);
        if (lane >= off && g2 == seg) { sum += s2; cnt += c2; }
    }

    // Run tails flush once per cross-thread run.
    int  seg_next = __shfl_down(seg, 1);
    bool tail     = (lane == 63) || (seg_next != seg);
    if (seg >= 0 && tail) {
        atomicAdd(sums + seg, sum);
        atomicAdd(counts + seg, cnt);
    }
}

__global__ __launch_bounds__(256) void finalize_kernel(
        const float* __restrict__ sums,
        const float* __restrict__ counts,
        float* __restrict__ out, int n) {
    int g = blockIdx.x * blockDim.x + threadIdx.x;
    if (g < n) out[g] = sums[g] / counts[g];
}

extern "C" void kernel_launch(void* const* d_in, const int* in_sizes, int n_in,
                              void* d_out, int out_size, void* d_ws, size_t ws_size,
                              hipStream_t stream) {
    const float* x     = (const float*)d_in[0];
    const int*   batch = (const int*)  d_in[3];
    int n_nodes = in_sizes[3];                 // 1,000,000

    float* sums   = (float*)d_ws;              // [N_GRAPHS]
    float* counts = sums + N_GRAPHS;           // [N_GRAPHS]

    // 1) zero accumulators (ws is poisoned 0xAA before every timed launch)
    {
        int n = 2 * N_GRAPHS;
        zero_ws_kernel<<<(n + 255) / 256, 256, 0, stream>>>((float*)d_ws, n);
    }

    // 2) accumulate per-segment (sum, count), 4 nodes per thread
    int n_chunks = (n_nodes + 3) / 4;          // 250,000
    accum_kernel<<<(n_chunks + 255) / 256, 256, 0, stream>>>(
        x, batch, sums, counts, n_chunks, n_nodes);

    // 3) divide
    finalize_kernel<<<(out_size + 255) / 256, 256, 0, stream>>>(
        sums, counts, (float*)d_out, out_size);
}